// Round 10
// baseline (381.226 us; speedup 1.0000x reference)
//
#include <hip/hip_runtime.h>

#define HIDDEN 128
#define NEG_SLOPE 0.2f
#define P_SORT 256          // blocks for phase-1 bucket sort

typedef unsigned short ushort_t;
typedef __attribute__((ext_vector_type(8))) short short8;
typedef __attribute__((ext_vector_type(4))) float floatx4;

static inline size_t align_up(size_t x, size_t a){ return (x + a - 1) & ~(a - 1); }

__device__ __forceinline__ ushort_t f2b(float f){
  unsigned u = __float_as_uint(f);
  unsigned r = (u + 0x7FFFu + ((u >> 16) & 1u)) >> 16;
  return (ushort_t)r;
}

__device__ __forceinline__ void fma8(float* acc, uint4 v, float a){
  acc[0] += a * __uint_as_float(v.x << 16);
  acc[1] += a * __uint_as_float(v.x & 0xFFFF0000u);
  acc[2] += a * __uint_as_float(v.y << 16);
  acc[3] += a * __uint_as_float(v.y & 0xFFFF0000u);
  acc[4] += a * __uint_as_float(v.z << 16);
  acc[5] += a * __uint_as_float(v.z & 0xFFFF0000u);
  acc[6] += a * __uint_as_float(v.w << 16);
  acc[7] += a * __uint_as_float(v.w & 0xFFFF0000u);
}

__device__ __forceinline__ uint4 pack8(const float* f){
  uint4 u;
  u.x = (unsigned)f2b(f[0]) | ((unsigned)f2b(f[1]) << 16);
  u.y = (unsigned)f2b(f[2]) | ((unsigned)f2b(f[3]) << 16);
  u.z = (unsigned)f2b(f[4]) | ((unsigned)f2b(f[5]) << 16);
  u.w = (unsigned)f2b(f[6]) | ((unsigned)f2b(f[7]) << 16);
  return u;
}

// ============ CSR build: two-pass bucketed counting sort (verified round 4) ============

__global__ __launch_bounds__(256) void k_b1cnt(const int* __restrict__ dst,
                                               int* __restrict__ bcnt,
                                               int E, int epb, int nbkt){
  __shared__ unsigned c[256];
  int t = threadIdx.x;
  c[t] = 0;
  __syncthreads();
  int e0 = blockIdx.x * epb;
  int e1 = min(E, e0 + epb);
  for (int e = e0 + t; e < e1; e += 256) atomicAdd(&c[dst[e] >> 8], 1u);
  __syncthreads();
  if (t < nbkt) bcnt[t * P_SORT + blockIdx.x] = (int)c[t];
}

__global__ void k_scan1(const int* __restrict__ in, int* __restrict__ incl,
                        int* __restrict__ blockSums, int M){
  __shared__ int sd[256];
  int t = threadIdx.x;
  int i = blockIdx.x*256 + t;
  int v = (i < M) ? in[i] : 0;
  sd[t] = v; __syncthreads();
  for (int off = 1; off < 256; off <<= 1){
    int add = (t >= off) ? sd[t-off] : 0;
    __syncthreads();
    sd[t] += add;
    __syncthreads();
  }
  if (i < M) incl[i] = sd[t];
  if (t == 255) blockSums[blockIdx.x] = sd[255];
}

__global__ void k_scan2(const int* __restrict__ blockSums, int* __restrict__ blockOffs, int nb){
  __shared__ int sd[256];
  __shared__ int carry;
  int t = threadIdx.x;
  if (t == 0) carry = 0;
  __syncthreads();
  for (int base = 0; base < nb; base += 256){
    int i = base + t;
    int v = (i < nb) ? blockSums[i] : 0;
    sd[t] = v; __syncthreads();
    for (int off = 1; off < 256; off <<= 1){
      int add = (t >= off) ? sd[t-off] : 0;
      __syncthreads();
      sd[t] += add;
      __syncthreads();
    }
    if (i < nb) blockOffs[i] = carry + sd[t] - v;
    __syncthreads();
    if (t == 0) carry += sd[255];
    __syncthreads();
  }
}

// phase-1 scatter: per-(bucket,block) base rebuilt in LDS from incl/bcnt/blockOffs
__global__ __launch_bounds__(256) void k_b1place(const int* __restrict__ src,
                                                 const int* __restrict__ dst,
                                                 const float* __restrict__ w,
                                                 const int* __restrict__ incl,
                                                 const int* __restrict__ bcnt,
                                                 const int* __restrict__ blockOffs,
                                                 int2* __restrict__ tpw,
                                                 int E, int epb, int nbkt){
  __shared__ int base_[256];
  __shared__ unsigned c[256];
  int t = threadIdx.x;
  c[t] = 0;
  if (t < nbkt){
    int idx = t * P_SORT + blockIdx.x;
    base_[t] = incl[idx] - bcnt[idx] + blockOffs[t];
  }
  __syncthreads();
  int e0 = blockIdx.x * epb;
  int e1 = min(E, e0 + epb);
  for (int e = e0 + t; e < e1; e += 256){
    int d = dst[e];
    int b = d >> 8;
    unsigned r = atomicAdd(&c[b], 1u);
    int pos = base_[b] + (int)r;
    tpw[pos] = make_int2((int)((unsigned)src[e] | ((unsigned)(d & 255) << 16)),
                         __float_as_int(w[e]));
  }
}

// phase-2 fine sort: bucket start = blockOffs[b]; writes rowp, packed (src,w), dinv
__global__ __launch_bounds__(256) void k_b2(const int2* __restrict__ tpw,
                                            const int* __restrict__ blockOffs,
                                            int2* __restrict__ col_sw,
                                            int* __restrict__ rowp,
                                            float* __restrict__ dinv,
                                            int N, int E, int nbkt){
  __shared__ unsigned hcnt[256];
  __shared__ int sd[256];
  __shared__ int lofs[256];
  __shared__ unsigned rcnt[256];
  __shared__ float wsum[256];
  int b = blockIdx.x, t = threadIdx.x;
  int e0 = blockOffs[b];
  int e1 = (b + 1 < nbkt) ? blockOffs[b + 1] : E;
  hcnt[t] = 0; rcnt[t] = 0; wsum[t] = 0.f;
  __syncthreads();
  for (int e = e0 + t; e < e1; e += 256)
    atomicAdd(&hcnt[((unsigned)tpw[e].x >> 16) & 255u], 1u);
  __syncthreads();
  int v = (int)hcnt[t];
  sd[t] = v; __syncthreads();
  for (int off = 1; off < 256; off <<= 1){
    int add = (t >= off) ? sd[t-off] : 0;
    __syncthreads();
    sd[t] += add;
    __syncthreads();
  }
  lofs[t] = sd[t] - v;
  int node = b*256 + t;
  if (node < N) rowp[node] = e0 + sd[t] - v;
  if (b == 0 && t == 0) rowp[N] = E;
  __syncthreads();
  for (int e = e0 + t; e < e1; e += 256){
    int2 pw = tpw[e];
    unsigned dl = ((unsigned)pw.x >> 16) & 255u;
    unsigned r = atomicAdd(&rcnt[dl], 1u);
    int pos = e0 + lofs[dl] + (int)r;
    col_sw[pos] = make_int2((int)((unsigned)pw.x & 0xFFFFu), pw.y);
    atomicAdd(&wsum[dl], __int_as_float(pw.y));
  }
  __syncthreads();
  if (node < N) dinv[node] = rsqrtf(wsum[t] + 1.0f);   // +1 = self-loop weight
}

// ---------------- weight cast (4 mats fp32 -> transposed bf16) ----------------

__global__ void k_cast_w(const float* __restrict__ Wg, const float* __restrict__ Wc,
                         ushort_t* __restrict__ Wt){
  int i = blockIdx.x*256 + threadIdx.x;       // 4*16384
  int mat = i >> 14, idx = i & 16383;
  int k = idx >> 7, n = idx & 127;
  float v = (mat == 0) ? Wg[idx] : Wc[(mat-1)*16384 + idx];
  Wt[mat*16384 + n*128 + k] = f2b(v);
}

// ------- MFMA GEMM, 16 rows/wave (64/block) for occupancy; DOTS=1: fp32 A + fused dots -------
template<int DOTS>
__global__ __launch_bounds__(256) void k_gemm(const void* __restrict__ Ain,
                                              const ushort_t* __restrict__ Wt,
                                              ushort_t* __restrict__ C,
                                              const float* __restrict__ a_src,
                                              const float* __restrict__ a_dst,
                                              const float* __restrict__ dinv,
                                              float2* __restrict__ attr,
                                              float* __restrict__ sdst, int M){
  int wave = threadIdx.x >> 6, l = threadIdx.x & 63;
  int q = l >> 4, lm = l & 15;
  int rowBase = blockIdx.x*64 + wave*16;
  floatx4 acc[8];
  #pragma unroll
  for (int nt = 0; nt < 8; nt++) acc[nt] = (floatx4){0.f,0.f,0.f,0.f};

  #pragma unroll
  for (int kc = 0; kc < 4; kc++){
    int k0 = kc*32 + q*8;
    short8 a;
    long r = rowBase + lm;
    if (r < M){
      if (DOTS){
        const float* ap = (const float*)Ain + r*128 + k0;
        float4 u = *(const float4*)ap;
        float4 v = *(const float4*)(ap + 4);
        short8 tv;
        tv[0]=(short)f2b(u.x); tv[1]=(short)f2b(u.y); tv[2]=(short)f2b(u.z); tv[3]=(short)f2b(u.w);
        tv[4]=(short)f2b(v.x); tv[5]=(short)f2b(v.y); tv[6]=(short)f2b(v.z); tv[7]=(short)f2b(v.w);
        a = tv;
      } else {
        a = *(const short8*)((const ushort_t*)Ain + r*128 + k0);
      }
    } else a = (short8){0,0,0,0,0,0,0,0};
    #pragma unroll
    for (int nt = 0; nt < 8; nt++){
      short8 b = *(const short8*)(Wt + (nt*16 + lm)*128 + k0);
      acc[nt] = __builtin_amdgcn_mfma_f32_16x16x32_bf16(a, b, acc[nt], 0, 0, 0);
    }
  }
  #pragma unroll
  for (int r = 0; r < 4; r++){
    long row = rowBase + q*4 + r;
    if (row < M){
      #pragma unroll
      for (int nt = 0; nt < 8; nt++)
        C[row*128 + nt*16 + lm] = f2b(acc[nt][r]);
    }
  }
  if (DOTS){
    float as8[8], ad8[8];
    #pragma unroll
    for (int nt = 0; nt < 8; nt++){ as8[nt] = a_src[nt*16 + lm]; ad8[nt] = a_dst[nt*16 + lm]; }
    #pragma unroll
    for (int r = 0; r < 4; r++){
      float ps = 0.f, pd = 0.f;
      #pragma unroll
      for (int nt = 0; nt < 8; nt++){
        ps += acc[nt][r] * as8[nt];
        pd += acc[nt][r] * ad8[nt];
      }
      #pragma unroll
      for (int off = 1; off <= 8; off <<= 1){
        ps += __shfl_xor(ps, off, 64);
        pd += __shfl_xor(pd, off, 64);
      }
      long row = rowBase + q*4 + r;
      if (lm == 0 && row < M){
        attr[row] = make_float2(ps, dinv[row]);
        sdst[row] = pd;
      }
    }
  }
}

// ======= aggregation: 512-thr blocks (8 waves), wave per node, 24 edges in flight =======
// MODE 0: GAT + fused postprocess; MODE 1: GCN mid (ReLU); MODE 2: GCN last + JK -> fp32 out
template<int MODE>
__global__ __launch_bounds__(512) void k_agg(const ushort_t* __restrict__ feat,
                                             const int* __restrict__ rowp,
                                             const int2* __restrict__ col_sw,
                                             int2* __restrict__ col_en,
                                             int2* __restrict__ col_ea,
                                             const float2* __restrict__ attr,
                                             const float* __restrict__ sdst_,
                                             const float* __restrict__ dinv,
                                             const float* __restrict__ bias,
                                             ushort_t* __restrict__ out,
                                             const uint4* __restrict__ j0,
                                             const uint4* __restrict__ j1,
                                             const uint4* __restrict__ j2,
                                             float4* __restrict__ yout, int N){
  int n = blockIdx.x*8 + (threadIdx.x >> 6);
  if (n >= N) return;
  int l = threadIdx.x & 63;
  int rs = rowp[n], re = rowp[n+1];
  float inv = 0.f, pself = 0.f;
  if (MODE == 0){
    float2 an = attr[n];
    float sdd = sdst_[n];
    float es = an.x + sdd;
    es = (es >= 0.f) ? es : NEG_SLOPE*es;
    pself = __expf(es);
    float ps = 0.f;
    for (int j = rs + l; j < re; j += 64){
      int2 sw = col_sw[j];
      float w = __int_as_float(sw.y);
      float2 a = attr[sw.x];
      col_en[j] = make_int2(sw.x, __float_as_int(a.y * w * an.y));
      float ee = a.x + sdd;
      ee = (ee >= 0.f) ? ee : NEG_SLOPE*ee;
      float pe = __expf(ee);
      ps += pe;
      col_ea[j] = make_int2(sw.x, __float_as_int(pe));
    }
    #pragma unroll
    for (int off = 32; off >= 1; off >>= 1) ps += __shfl_xor(ps, off, 64);
    inv = 1.f / (ps + pself);
  }
  const int2* col = (MODE == 0) ? (const int2*)col_ea : (const int2*)col_en;
  int sub = l >> 4, q = l & 15;               // 4 edge slots x 16B-quads, 6-deep unroll
  const uint4* f16 = (const uint4*)feat;
  float acc[8] = {0.f,0.f,0.f,0.f,0.f,0.f,0.f,0.f};
  for (int base = rs; base < re; base += 24){
    int2 p[6]; float a[6];
    #pragma unroll
    for (int j = 0; j < 6; j++){
      int e = base + sub + 4*j;
      int cc = min(e, re-1);
      p[j] = col[cc];
      a[j] = (e < re) ? __int_as_float(p[j].y) : 0.f;
    }
    uint4 v[6];
    #pragma unroll
    for (int j = 0; j < 6; j++) v[j] = f16[(size_t)p[j].x*16 + q];
    #pragma unroll
    for (int j = 0; j < 6; j++) fma8(acc, v[j], a[j]);
  }
  #pragma unroll
  for (int j = 0; j < 8; j++){
    acc[j] += __shfl_xor(acc[j], 16, 64);
    acc[j] += __shfl_xor(acc[j], 32, 64);
  }
  if (sub == 0){
    float sc;
    if (MODE == 0){
      #pragma unroll
      for (int j = 0; j < 8; j++) acc[j] *= inv;
      sc = pself * inv;
    } else {
      float di = dinv[n];
      sc = di * di;                           // self-loop norm (w=1)
    }
    uint4 v = f16[(size_t)n*16 + q];
    fma8(acc, v, sc);
    float4 b0 = ((const float4*)bias)[q*2];
    float4 b1 = ((const float4*)bias)[q*2 + 1];
    acc[0]+=b0.x; acc[1]+=b0.y; acc[2]+=b0.z; acc[3]+=b0.w;
    acc[4]+=b1.x; acc[5]+=b1.y; acc[6]+=b1.z; acc[7]+=b1.w;
    if (MODE >= 1){
      #pragma unroll
      for (int j = 0; j < 8; j++) acc[j] = fmaxf(acc[j], 0.f);
    }
    if (MODE <= 1){
      ((uint4*)out)[(size_t)n*16 + q] = pack8(acc);
    } else {
      size_t qi = (size_t)n*16 + q;
      uint4 a0 = j0[qi], a1 = j1[qi], a2 = j2[qi];
      float m[8];
      #pragma unroll
      for (int k = 0; k < 4; k++){
        unsigned u0 = (&a0.x)[k], u1 = (&a1.x)[k], u2 = (&a2.x)[k];
        float lo = fmaxf(fmaxf(__uint_as_float(u0 << 16), __uint_as_float(u1 << 16)),
                         __uint_as_float(u2 << 16));
        float hi = fmaxf(fmaxf(__uint_as_float(u0 & 0xFFFF0000u), __uint_as_float(u1 & 0xFFFF0000u)),
                         __uint_as_float(u2 & 0xFFFF0000u));
        m[k*2]   = fmaxf(acc[k*2],   lo);
        m[k*2+1] = fmaxf(acc[k*2+1], hi);
      }
      size_t yi = (size_t)n*32 + q*2;
      yout[yi]   = make_float4(m[0], m[1], m[2], m[3]);
      yout[yi+1] = make_float4(m[4], m[5], m[6], m[7]);
    }
  }
}

extern "C" void kernel_launch(void* const* d_in, const int* in_sizes, int n_in,
                              void* d_out, int out_size, void* d_ws, size_t ws_size,
                              hipStream_t stream){
  const float* x      = (const float*)d_in[0];
  const int*   eidx   = (const int*)d_in[1];
  const float* emask  = (const float*)d_in[2];
  const float* W_gat  = (const float*)d_in[3];
  const float* a_src  = (const float*)d_in[4];
  const float* a_dst  = (const float*)d_in[5];
  const float* b_gat  = (const float*)d_in[6];
  const float* W_gcn  = (const float*)d_in[7];
  const float* b_gcn  = (const float*)d_in[8];
  int N = in_sizes[0] / HIDDEN;
  int E = in_sizes[1] / 2;
  const int* src = eidx;
  const int* dst = eidx + E;

  char* p = (char*)d_ws;
  auto carve = [&](size_t bytes)->char*{ char* q = p; p += align_up(bytes, 512); return q; };
  ushort_t* zb   = (ushort_t*)carve((size_t)N*HIDDEN*2);
  ushort_t* h0   = (ushort_t*)carve((size_t)N*HIDDEN*2);
  ushort_t* h1   = (ushort_t*)carve((size_t)N*HIDDEN*2);
  ushort_t* h2   = (ushort_t*)carve((size_t)N*HIDDEN*2);
  ushort_t* Wt   = (ushort_t*)carve((size_t)4*HIDDEN*HIDDEN*2);
  float2* attr   = (float2*)carve((size_t)N*8);
  float* sdst    = (float*)carve((size_t)N*4);
  float* dinv    = (float*)carve((size_t)N*4);
  int*   rowp    = (int*)  carve((size_t)(N+1)*4);
  int2*  col_sw  = (int2*) carve((size_t)E*8);
  int2*  col_en  = (int2*) carve((size_t)E*8);
  int2*  col_ea  = (int2*) carve((size_t)E*8);
  int2*  tpw     = (int2*) carve((size_t)E*8);
  int nbkt = (N + 255) >> 8;                       // 196
  int M    = nbkt * P_SORT;                        // 50176
  int*   bcnt  = (int*)carve((size_t)M*4);
  int*   incl  = (int*)carve((size_t)M*4);
  int nbs = (M + 255) / 256;                       // == nbkt
  int*   blockSums = (int*)carve((size_t)nbs*4);
  int*   blockOffs = (int*)carve((size_t)nbs*4);
  (void)ws_size; (void)n_in; (void)out_size;

  int epb = (E + P_SORT - 1) / P_SORT;
  int gb  = (N + 63) / 64;                         // 16 rows/wave, 64 rows/block
  int nab = (N + 7) / 8;                           // 512-thread agg blocks

  // CSR build (atomic-free, full-chip)
  k_b1cnt  <<<P_SORT, 256, 0, stream>>>(dst, bcnt, E, epb, nbkt);
  k_scan1  <<<nbs, 256, 0, stream>>>(bcnt, incl, blockSums, M);
  k_scan2  <<<1,   256, 0, stream>>>(blockSums, blockOffs, nbs);
  k_b1place<<<P_SORT, 256, 0, stream>>>(src, dst, emask, incl, bcnt, blockOffs,
                                        tpw, E, epb, nbkt);
  k_b2     <<<nbkt, 256, 0, stream>>>(tpw, blockOffs, col_sw, rowp, dinv, N, E, nbkt);

  // weights
  k_cast_w<<<(4*HIDDEN*HIDDEN)/256, 256, 0, stream>>>(W_gat, W_gcn, Wt);

  // xp = x @ W_gat (fp32 A direct), fused s_src/s_dst dots + dinv pack
  k_gemm<1><<<gb, 256, 0, stream>>>((const void*)x, Wt, zb, a_src, a_dst, dinv, attr, sdst, N);

  // GAT aggregation with fused edge postprocess
  k_agg<0><<<nab, 512, 0, stream>>>(zb, rowp, col_sw, col_en, col_ea, attr, sdst,
                                    dinv, b_gat, h0, nullptr, nullptr, nullptr, nullptr, N);

  ushort_t* hs[3] = {h0, h1, h2};
  for (int l = 0; l < 2; l++){
    k_gemm<0><<<gb, 256, 0, stream>>>((const void*)hs[l], Wt + (size_t)(l+1)*HIDDEN*HIDDEN,
                                      zb, a_src, a_dst, dinv, attr, sdst, N);
    k_agg<1><<<nab, 512, 0, stream>>>(zb, rowp, col_sw, col_en, col_ea, attr, sdst,
                                      dinv, b_gcn + (size_t)l*HIDDEN, hs[l+1],
                                      nullptr, nullptr, nullptr, nullptr, N);
  }
  // last layer: GEMM then aggregation with fused JK-max -> fp32 d_out
  k_gemm<0><<<gb, 256, 0, stream>>>((const void*)h2, Wt + (size_t)3*HIDDEN*HIDDEN,
                                    zb, a_src, a_dst, dinv, attr, sdst, N);
  k_agg<2><<<nab, 512, 0, stream>>>(zb, rowp, col_sw, col_en, col_ea, attr, sdst,
                                    dinv, b_gcn + (size_t)2*HIDDEN, nullptr,
                                    (const uint4*)h0, (const uint4*)h1, (const uint4*)h2,
                                    (float4*)d_out, N);
}